// Round 4
// baseline (357.483 us; speedup 1.0000x reference)
//
#include <hip/hip_runtime.h>

#define Bb 4
#define Cc 256
#define Nn 32768

typedef short s16x8 __attribute__((ext_vector_type(8)));
typedef float f32x4 __attribute__((ext_vector_type(4)));

__device__ __forceinline__ unsigned short bfh(float f) {
    union { float f; unsigned u; } c; c.f = f;
    unsigned u = c.u + 0x7fffu + ((c.u >> 16) & 1u);
    return (unsigned short)(u >> 16);
}
__device__ __forceinline__ unsigned fbits(float f) {
    union { float f; unsigned u; } c; c.f = f; return c.u;
}
__device__ __forceinline__ float fof(unsigned u) {
    union { unsigned u; float f; } c; c.u = u; return c.f;
}
__device__ __forceinline__ int swz(int l) { return l ^ ((l >> 3) & 6); }

// hi = trunc-bf16 (top 16 bits), lo = rtn-bf16 of residual. 8 floats -> 2x uint4.
__device__ __forceinline__ void cvt8(float4 A, float4 B, uint4& h, uint4& l) {
    unsigned a0 = fbits(A.x), a1 = fbits(A.y), a2 = fbits(A.z), a3 = fbits(A.w);
    unsigned b0 = fbits(B.x), b1 = fbits(B.y), b2 = fbits(B.z), b3 = fbits(B.w);
    h.x = __builtin_amdgcn_perm(a1, a0, 0x07060302u);
    h.y = __builtin_amdgcn_perm(a3, a2, 0x07060302u);
    h.z = __builtin_amdgcn_perm(b1, b0, 0x07060302u);
    h.w = __builtin_amdgcn_perm(b3, b2, 0x07060302u);
    unsigned l0 = fbits(A.x - fof(a0 & 0xffff0000u)) + 0x8000u;
    unsigned l1 = fbits(A.y - fof(a1 & 0xffff0000u)) + 0x8000u;
    unsigned l2 = fbits(A.z - fof(a2 & 0xffff0000u)) + 0x8000u;
    unsigned l3 = fbits(A.w - fof(a3 & 0xffff0000u)) + 0x8000u;
    unsigned m0 = fbits(B.x - fof(b0 & 0xffff0000u)) + 0x8000u;
    unsigned m1 = fbits(B.y - fof(b1 & 0xffff0000u)) + 0x8000u;
    unsigned m2 = fbits(B.z - fof(b2 & 0xffff0000u)) + 0x8000u;
    unsigned m3 = fbits(B.w - fof(b3 & 0xffff0000u)) + 0x8000u;
    l.x = __builtin_amdgcn_perm(l1, l0, 0x07060302u);
    l.y = __builtin_amdgcn_perm(l3, l2, 0x07060302u);
    l.z = __builtin_amdgcn_perm(m1, m0, 0x07060302u);
    l.w = __builtin_amdgcn_perm(m3, m2, 0x07060302u);
}
__device__ __forceinline__ float s4(float4 v) { return (v.x + v.y) + (v.z + v.w); }

// ---------------- Gram partials via bf16x3 MFMA, 128x128 tiles ---------------
// tile (ti,tj) of (b,ks): S[ti*128+.., tj*128+..] over k-slice ks.
// 4 sibling tiles share X/Y slices -> grouped on one XCD via chunked swizzle.
__global__ __launch_bounds__(256, 3) void k_gram(const float* __restrict__ x,
                                                 const float* __restrict__ y,
                                                 float* __restrict__ part,
                                                 float* __restrict__ sxp,
                                                 float* __restrict__ syp,
                                                 int nsplit) {
    int G = Bb * nsplit * 4;                 // grid size, multiple of 8
    int chunk = G >> 3;
    int lid = blockIdx.x;
    int bid = (lid & 7) * chunk + (lid >> 3);   // bijective XCD-chunk swizzle

    int tile = bid & 3;
    int ti = tile >> 1, tj = tile & 1;
    int ks = (bid >> 2) % nsplit;
    int b  = bid / (4 * nsplit);
    int Kblk = Nn / nsplit;
    int nstep = Kblk >> 5;

    const float* X = x + (size_t)b * Cc * Nn + (size_t)(ti * 128) * Nn + (size_t)ks * Kblk;
    const float* Y = y + (size_t)b * Cc * Nn + (size_t)(tj * 128) * Nn + (size_t)ks * Kblk;

    __shared__ __align__(16) short XH[4096], XL[4096];   // 8 frags x 64 lanes x 8
    __shared__ __align__(16) short YH[4096], YL[4096];   // 32 KB total

    int tid = threadIdx.x;
    int lane = tid & 63;
    int wave = tid >> 6;
    int wr = wave >> 1, wc = wave & 1;
    int r = tid >> 1, kh = tid & 1;          // staging: row r (0..127), k-half

    const float* px = X + (size_t)r * Nn + kh * 16;
    const float* py = Y + (size_t)r * Nn + kh * 16;

    int tr = r >> 4, rr = r & 15;
    int l0 = rr + 32 * kh, l1 = l0 + 16;
    int o0 = (tr * 64 + swz(l0)) * 8, o1 = (tr * 64 + swz(l1)) * 8;

    f32x4 acc[4][4];
    #pragma unroll
    for (int i = 0; i < 4; ++i)
        #pragma unroll
        for (int j = 0; j < 4; ++j)
            #pragma unroll
            for (int z = 0; z < 4; ++z) acc[i][j][z] = 0.f;

    float4 F[8];
    float xsum = 0.f, ysum = 0.f;

    #define LOADF(kb) do { \
        F[0] = ((const float4*)(px + (kb)))[0]; F[1] = ((const float4*)(px + (kb)))[1]; \
        F[2] = ((const float4*)(px + (kb)))[2]; F[3] = ((const float4*)(px + (kb)))[3]; \
        F[4] = ((const float4*)(py + (kb)))[0]; F[5] = ((const float4*)(py + (kb)))[1]; \
        F[6] = ((const float4*)(py + (kb)))[2]; F[7] = ((const float4*)(py + (kb)))[3]; \
    } while (0)

    LOADF(0);
    for (int t = 0; t < nstep; ++t) {
        uint4 hx0, hx1, hy0, hy1, qx0, qx1, qy0, qy1;
        cvt8(F[0], F[1], hx0, qx0);  cvt8(F[2], F[3], hx1, qx1);
        cvt8(F[4], F[5], hy0, qy0);  cvt8(F[6], F[7], hy1, qy1);
        xsum += s4(F[0]) + s4(F[1]) + s4(F[2]) + s4(F[3]);
        ysum += s4(F[4]) + s4(F[5]) + s4(F[6]) + s4(F[7]);
        if (t + 1 < nstep) LOADF((t + 1) * 32);   // in flight across both phases
        __syncthreads();                 // previous compute finished reading LDS
        *(uint4*)&XH[o0] = hx0; *(uint4*)&XL[o0] = qx0;
        *(uint4*)&XH[o1] = hx1; *(uint4*)&XL[o1] = qx1;
        *(uint4*)&YH[o0] = hy0; *(uint4*)&YL[o0] = qy0;
        *(uint4*)&YH[o1] = hy1; *(uint4*)&YL[o1] = qy1;
        __syncthreads();
        {
            int sl = swz(lane);
            s16x8 ah[4], al[4];
            #pragma unroll
            for (int i = 0; i < 4; ++i) {
                int fr = (wr * 4 + i) * 64 + sl;
                ah[i] = *(const s16x8*)&XH[fr * 8];
                al[i] = *(const s16x8*)&XL[fr * 8];
            }
            #pragma unroll
            for (int j = 0; j < 4; ++j) {
                int fr = (wc * 4 + j) * 64 + sl;
                s16x8 bh = *(const s16x8*)&YH[fr * 8];
                s16x8 bl = *(const s16x8*)&YL[fr * 8];
                #pragma unroll
                for (int i = 0; i < 4; ++i) {
                    acc[i][j] = __builtin_amdgcn_mfma_f32_16x16x32_bf16(ah[i], bh, acc[i][j], 0, 0, 0);
                    acc[i][j] = __builtin_amdgcn_mfma_f32_16x16x32_bf16(ah[i], bl, acc[i][j], 0, 0, 0);
                    acc[i][j] = __builtin_amdgcn_mfma_f32_16x16x32_bf16(al[i], bh, acc[i][j], 0, 0, 0);
                }
            }
        }
    }
    #undef LOADF

    // row-sum partials (deterministic, counted once: X by tj==0, Y by ti==0)
    float xs = xsum + __shfl_down(xsum, 1);
    float ys = ysum + __shfl_down(ysum, 1);
    if (!(tid & 1)) {
        if (tj == 0) sxp[((size_t)b * nsplit + ks) * 256 + ti * 128 + r] = xs;
        if (ti == 0) syp[((size_t)b * nsplit + ks) * 256 + tj * 128 + r] = ys;
    }

    // write partials (C/D: col = lane&15, row = (lane>>4)*4 + reg)
    float* P = part + ((size_t)b * nsplit + ks) * Cc * Cc;
    #pragma unroll
    for (int i = 0; i < 4; ++i)
        #pragma unroll
        for (int j = 0; j < 4; ++j)
            #pragma unroll
            for (int reg = 0; reg < 4; ++reg) {
                int gi = ti * 128 + wr * 64 + i * 16 + (lane >> 4) * 4 + reg;
                int gj = tj * 128 + wc * 64 + j * 16 + (lane & 15);
                P[(size_t)gi * Cc + gj] = acc[i][j][reg];
            }
}

// reduce S partials; blocks >=1024 reduce row-sum partials into sx/sy
__global__ __launch_bounds__(256) void k_reduceS(const float* __restrict__ part,
                                                 const float* __restrict__ sxp,
                                                 const float* __restrict__ syp,
                                                 float* __restrict__ S,
                                                 float* __restrict__ sx,
                                                 float* __restrict__ sy, int split) {
    if (blockIdx.x < 1024) {
        int t = blockIdx.x * 256 + threadIdx.x;   // 0..262143
        int b = t >> 16;
        int rc = t & 65535;
        float s = 0.f;
        for (int ks = 0; ks < split; ++ks)
            s += part[(((size_t)b * split + ks) << 16) + rc];
        S[t] = s;
    } else {
        int flat = (blockIdx.x - 1024) * 256 + threadIdx.x;  // 0..2047
        int b = flat >> 9, rem = flat & 511, which = rem >> 8, c = rem & 255;
        const float* src = (which ? syp : sxp) + (size_t)b * split * 256 + c;
        float s = 0.f;
        for (int ks = 0; ks < split; ++ks) s += src[(size_t)ks * 256];
        (which ? sy : sx)[b * 256 + c] = s;
    }
}

// qx[b,i] = Wq[i,:]·sx[b,:];  ky[b,j] = Wk[j,:]·sy[b,:]
__global__ __launch_bounds__(256) void k_qxky(const float* __restrict__ Wq,
                                              const float* __restrict__ Wk,
                                              const float* __restrict__ sx,
                                              const float* __restrict__ sy,
                                              float* __restrict__ qx,
                                              float* __restrict__ ky) {
    int t = blockIdx.x * 256 + threadIdx.x;   // 0..2047
    int which = t >> 10;
    int b = (t >> 8) & 3;
    int r = t & 255;
    const float* W  = which ? Wk : Wq;
    const float* sv = which ? sy : sx;
    float* dst      = which ? ky : qx;
    float s = 0.f;
    #pragma unroll 4
    for (int c = 0; c < Cc; ++c) s += W[r * Cc + c] * sv[b * Cc + c];
    dst[b * Cc + r] = s;
}

// T1[b,c,j] = sum_d S[b,c,d] * Wk[j,d]
__global__ __launch_bounds__(256) void k_T1(const float* __restrict__ S,
                                            const float* __restrict__ Wk,
                                            float* __restrict__ T1) {
    int b = blockIdx.x >> 8;
    int c = blockIdx.x & 255;
    int j = threadIdx.x;
    __shared__ float srow[256];
    srow[j] = S[((size_t)b * Cc + c) * Cc + j];
    __syncthreads();
    const float4* wk4 = (const float4*)(Wk + (size_t)j * Cc);
    const float4* sr4 = (const float4*)srow;
    float s = 0.f;
    #pragma unroll 4
    for (int d = 0; d < Cc / 4; ++d) {
        float4 a = sr4[d]; float4 w = wk4[d];
        s += a.x * w.x + a.y * w.y + a.z * w.z + a.w * w.w;
    }
    T1[((size_t)b * Cc + c) * Cc + j] = s;
}

// scores + softmax + cbias:  one block per (b,i) row
__global__ __launch_bounds__(256) void k_scores_softmax(const float* __restrict__ T1,
                                                        const float* __restrict__ Wq,
                                                        const float* __restrict__ bq,
                                                        const float* __restrict__ bk,
                                                        const float* __restrict__ qx,
                                                        const float* __restrict__ ky,
                                                        const float* __restrict__ bv,
                                                        float* __restrict__ Wt,
                                                        float* __restrict__ cbias) {
    int b = blockIdx.x >> 8;
    int i = blockIdx.x & 255;
    int j = threadIdx.x;
    __shared__ float wq[256];
    wq[j] = Wq[i * Cc + j];
    __syncthreads();
    const float* t1 = T1 + (size_t)b * Cc * Cc + j;
    float s = 0.f;
    #pragma unroll 4
    for (int c = 0; c < Cc; ++c) s += wq[c] * t1[(size_t)c * Cc];
    s += qx[b * Cc + i] * bk[j] + bq[i] * (ky[b * Cc + j] + 32768.0f * bk[j]);

    __shared__ float red[256];
    red[j] = s; __syncthreads();
    for (int st = 128; st > 0; st >>= 1) {
        if (j < st) red[j] = fmaxf(red[j], red[j + st]);
        __syncthreads();
    }
    float mx = red[0];
    __syncthreads();
    float e = expf(s - mx);
    red[j] = e; __syncthreads();
    for (int st = 128; st > 0; st >>= 1) {
        if (j < st) red[j] += red[j + st];
        __syncthreads();
    }
    float w = e / red[0];
    Wt[((size_t)b * Cc + i) * Cc + j] = w;
    __syncthreads();
    red[j] = w * bv[j]; __syncthreads();
    for (int st = 128; st > 0; st >>= 1) {
        if (j < st) red[j] += red[j + st];
        __syncthreads();
    }
    if (j == 0) cbias[b * Cc + i] = red[0];
}

// M[b,i,c] = sum_j Wt[b,i,j] * Wv[j,c]   -> bf16
__global__ __launch_bounds__(256) void k_M(const float* __restrict__ Wt,
                                           const float* __restrict__ Wv,
                                           short* __restrict__ Mbf) {
    int b = blockIdx.x >> 8;
    int i = blockIdx.x & 255;
    int c = threadIdx.x;
    __shared__ float wrow[256];
    wrow[c] = Wt[((size_t)b * Cc + i) * Cc + c];
    __syncthreads();
    float m = 0.f;
    #pragma unroll 4
    for (int j = 0; j < Cc; ++j) m += wrow[j] * Wv[(size_t)j * Cc + c];
    Mbf[((size_t)b * Cc + i) * Cc + c] = (short)bfh(m);
}

// out[b,i,n] = sum_c M[b,i,c]*y[b,c,n] + cb[b,i]   (bf16 MFMA, Y prefetched)
__global__ __launch_bounds__(256, 2) void k_out_mfma(const short* __restrict__ Mbf,
                                                     const float* __restrict__ y,
                                                     const float* __restrict__ cb,
                                                     float* __restrict__ out) {
    int tid = threadIdx.x;
    int lane = tid & 63;
    int wave = tid >> 6;
    int bid = blockIdx.x;           // 0..1023
    int b = bid >> 8, grp = bid & 255;
    int nbase = grp * 128 + wave * 32;
    const float* Y = y + (size_t)b * Cc * Nn;
    const short* M = Mbf + (size_t)b * Cc * Cc;

    f32x4 acc[16][2];
    #pragma unroll
    for (int ti = 0; ti < 16; ++ti)
        #pragma unroll
        for (int nb = 0; nb < 2; ++nb)
            #pragma unroll
            for (int z = 0; z < 4; ++z) acc[ti][nb][z] = 0.f;

    float yv0[8], yv1[8];
    {
        int c0 = 8 * (lane >> 4);
        #pragma unroll
        for (int j = 0; j < 8; ++j) {
            yv0[j] = Y[(size_t)(c0 + j) * Nn + nbase + (lane & 15)];
            yv1[j] = Y[(size_t)(c0 + j) * Nn + nbase + 16 + (lane & 15)];
        }
    }
    for (int s = 0; s < 8; ++s) {
        int c0 = 32 * s + 8 * (lane >> 4);
        s16x8 bf0, bf1;
        #pragma unroll
        for (int j = 0; j < 8; ++j) {
            bf0[j] = (short)bfh(yv0[j]);
            bf1[j] = (short)bfh(yv1[j]);
        }
        if (s + 1 < 8) {                       // issue next-step loads early
            int c0n = 32 * (s + 1) + 8 * (lane >> 4);
            #pragma unroll
            for (int j = 0; j < 8; ++j) {
                yv0[j] = Y[(size_t)(c0n + j) * Nn + nbase + (lane & 15)];
                yv1[j] = Y[(size_t)(c0n + j) * Nn + nbase + 16 + (lane & 15)];
            }
        }
        #pragma unroll
        for (int ti = 0; ti < 16; ++ti) {
            s16x8 af = *(const s16x8*)&M[(size_t)(ti * 16 + (lane & 15)) * Cc + c0];
            acc[ti][0] = __builtin_amdgcn_mfma_f32_16x16x32_bf16(af, bf0, acc[ti][0], 0, 0, 0);
            acc[ti][1] = __builtin_amdgcn_mfma_f32_16x16x32_bf16(af, bf1, acc[ti][1], 0, 0, 0);
        }
    }
    #pragma unroll
    for (int ti = 0; ti < 16; ++ti)
        #pragma unroll
        for (int nb = 0; nb < 2; ++nb)
            #pragma unroll
            for (int reg = 0; reg < 4; ++reg) {
                int i = ti * 16 + (lane >> 4) * 4 + reg;
                out[((size_t)b * Cc + i) * Nn + nbase + nb * 16 + (lane & 15)] =
                    acc[ti][nb][reg] + cb[b * Cc + i];
            }
}

extern "C" void kernel_launch(void* const* d_in, const int* in_sizes, int n_in,
                              void* d_out, int out_size, void* d_ws, size_t ws_size,
                              hipStream_t stream) {
    const float* x  = (const float*)d_in[0];
    const float* y  = (const float*)d_in[1];
    const float* Wq = (const float*)d_in[2];
    const float* bq = (const float*)d_in[3];
    const float* Wk = (const float*)d_in[4];
    const float* bk = (const float*)d_in[5];
    const float* Wv = (const float*)d_in[6];
    const float* bv = (const float*)d_in[7];
    float* out = (float*)d_out;

    float* ws = (float*)d_ws;
    size_t off = 0;
    float* S  = ws + off; off += (size_t)Bb * Cc * Cc;
    float* sx = ws + off; off += Bb * Cc;
    float* sy = ws + off; off += Bb * Cc;
    float* qx = ws + off; off += Bb * Cc;
    float* ky = ws + off; off += Bb * Cc;
    float* T1 = ws + off; off += (size_t)Bb * Cc * Cc;
    float* Wt = ws + off; off += (size_t)Bb * Cc * Cc;
    short* Mbf = (short*)(ws + off); off += (size_t)Bb * Cc * Cc / 2;
    float* cb = ws + off; off += Bb * Cc;
    float* sxp = ws + off; off += (size_t)Bb * 64 * 256;
    float* syp = ws + off; off += (size_t)Bb * 64 * 256;
    float* part = ws + off;

    size_t avail = ws_size / 4 - off;
    int split = 64;                              // must divide 1024
    while (split > 16 && (size_t)split * Bb * Cc * Cc > avail) split >>= 1;

    k_gram<<<Bb * split * 4, 256, 0, stream>>>(x, y, part, sxp, syp, split);
    k_reduceS<<<1032, 256, 0, stream>>>(part, sxp, syp, S, sx, sy, split);
    k_qxky<<<8, 256, 0, stream>>>(Wq, Wk, sx, sy, qx, ky);
    k_T1<<<1024, 256, 0, stream>>>(S, Wk, T1);
    k_scores_softmax<<<1024, 256, 0, stream>>>(T1, Wq, bq, bk, qx, ky, bv, Wt, cb);
    k_M<<<1024, 256, 0, stream>>>(Wt, Wv, Mbf);
    k_out_mfma<<<1024, 256, 0, stream>>>(Mbf, y, cb, out);
}

// Round 5
// 308.543 us; speedup vs baseline: 1.1586x; 1.1586x over previous
//
#include <hip/hip_runtime.h>

#define Bb 4
#define Cc 256
#define Nn 32768

typedef short s16x8 __attribute__((ext_vector_type(8)));
typedef float f32x4 __attribute__((ext_vector_type(4)));

__device__ __forceinline__ unsigned short bfh(float f) {
    union { float f; unsigned u; } c; c.f = f;
    unsigned u = c.u + 0x7fffu + ((c.u >> 16) & 1u);
    return (unsigned short)(u >> 16);
}
__device__ __forceinline__ unsigned fbits(float f) {
    union { float f; unsigned u; } c; c.f = f; return c.u;
}
__device__ __forceinline__ float fof(unsigned u) {
    union { unsigned u; float f; } c; c.u = u; return c.f;
}
__device__ __forceinline__ int swz(int l) { return l ^ ((l >> 3) & 6); }

// hi = trunc-bf16 (top 16 bits), lo = rtn-bf16 of residual. 8 floats -> 2x uint4.
__device__ __forceinline__ void cvt8(float4 A, float4 B, uint4& h, uint4& l) {
    unsigned a0 = fbits(A.x), a1 = fbits(A.y), a2 = fbits(A.z), a3 = fbits(A.w);
    unsigned b0 = fbits(B.x), b1 = fbits(B.y), b2 = fbits(B.z), b3 = fbits(B.w);
    h.x = __builtin_amdgcn_perm(a1, a0, 0x07060302u);
    h.y = __builtin_amdgcn_perm(a3, a2, 0x07060302u);
    h.z = __builtin_amdgcn_perm(b1, b0, 0x07060302u);
    h.w = __builtin_amdgcn_perm(b3, b2, 0x07060302u);
    unsigned l0 = fbits(A.x - fof(a0 & 0xffff0000u)) + 0x8000u;
    unsigned l1 = fbits(A.y - fof(a1 & 0xffff0000u)) + 0x8000u;
    unsigned l2 = fbits(A.z - fof(a2 & 0xffff0000u)) + 0x8000u;
    unsigned l3 = fbits(A.w - fof(a3 & 0xffff0000u)) + 0x8000u;
    unsigned m0 = fbits(B.x - fof(b0 & 0xffff0000u)) + 0x8000u;
    unsigned m1 = fbits(B.y - fof(b1 & 0xffff0000u)) + 0x8000u;
    unsigned m2 = fbits(B.z - fof(b2 & 0xffff0000u)) + 0x8000u;
    unsigned m3 = fbits(B.w - fof(b3 & 0xffff0000u)) + 0x8000u;
    l.x = __builtin_amdgcn_perm(l1, l0, 0x07060302u);
    l.y = __builtin_amdgcn_perm(l3, l2, 0x07060302u);
    l.z = __builtin_amdgcn_perm(m1, m0, 0x07060302u);
    l.w = __builtin_amdgcn_perm(m3, m2, 0x07060302u);
}
__device__ __forceinline__ float s4(float4 v) { return (v.x + v.y) + (v.z + v.w); }

// ---------------- Gram partials via bf16x3 MFMA, 2-phase pipelined -----------
// Round-3 structure (128x256 tiles, 512 blocks = 2/CU exact) + XCD pair swizzle
// + load issue interleaved into conversion. Emits row-sum partials too.
__global__ __launch_bounds__(256, 2) void k_gram(const float* __restrict__ x,
                                                 const float* __restrict__ y,
                                                 float* __restrict__ part,
                                                 float* __restrict__ sxp,
                                                 float* __restrict__ syp,
                                                 int nsplit) {
    int G = Bb * nsplit * 2;                    // 512 when split=64; multiple of 8
    int chunk = G >> 3;
    int lid = blockIdx.x;
    int bid = (lid & 7) * chunk + (lid >> 3);   // bijective: sibling halves same XCD

    int half = bid & 1;
    int ks = (bid >> 1) % nsplit;
    int b = bid / (2 * nsplit);
    int Kblk = Nn / nsplit;
    int nstep = Kblk >> 5;

    const float* X = x + (size_t)b * Cc * Nn + (size_t)(half * 128) * Nn + (size_t)ks * Kblk;
    const float* Y = y + (size_t)b * Cc * Nn + (size_t)ks * Kblk;

    __shared__ __align__(16) short XH[4096], XL[4096];
    __shared__ __align__(16) short YH[8192], YL[8192];

    int tid = threadIdx.x;
    int lane = tid & 63;
    int wave = tid >> 6;
    int wr = wave >> 1, wc = wave & 1;
    int r = tid >> 1, kh = tid & 1;

    const float* px  = X + (size_t)r * Nn + kh * 16;
    const float* py0 = Y + (size_t)r * Nn + kh * 16;
    const float* py1 = Y + (size_t)(r + 128) * Nn + kh * 16;

    int tr = r >> 4, rr = r & 15;
    int l0 = rr + 32 * kh, l1 = l0 + 16;
    int xo0 = (tr * 64 + swz(l0)) * 8, xo1 = (tr * 64 + swz(l1)) * 8;
    int yo00 = (tr * 64 + swz(l0)) * 8, yo01 = (tr * 64 + swz(l1)) * 8;
    int yo10 = ((tr + 8) * 64 + swz(l0)) * 8, yo11 = ((tr + 8) * 64 + swz(l1)) * 8;

    f32x4 acc[4][8];
    #pragma unroll
    for (int i = 0; i < 4; ++i)
        #pragma unroll
        for (int j = 0; j < 8; ++j)
            #pragma unroll
            for (int z = 0; z < 4; ++z) acc[i][j][z] = 0.f;

    float4 F[12];
    float xsum = 0.f, ysum0 = 0.f, ysum1 = 0.f;

    F[0] = ((const float4*)px)[0];  F[1] = ((const float4*)px)[1];
    F[2] = ((const float4*)px)[2];  F[3] = ((const float4*)px)[3];
    F[4] = ((const float4*)py0)[0]; F[5] = ((const float4*)py0)[1];
    F[6] = ((const float4*)py0)[2]; F[7] = ((const float4*)py0)[3];
    F[8] = ((const float4*)py1)[0]; F[9] = ((const float4*)py1)[1];
    F[10] = ((const float4*)py1)[2]; F[11] = ((const float4*)py1)[3];

    for (int t = 0; t < nstep; ++t) {
        uint4 h0, h1, h2, h3, h4, h5, q0, q1, q2, q3, q4, q5;
        bool more = (t + 1 < nstep);
        int kb = (t + 1) * 32;
        // convert + sum, then immediately re-issue the freed registers' loads
        cvt8(F[0], F[1], h0, q0);
        cvt8(F[2], F[3], h1, q1);
        xsum += s4(F[0]) + s4(F[1]) + s4(F[2]) + s4(F[3]);
        if (more) {
            F[0] = ((const float4*)(px + kb))[0]; F[1] = ((const float4*)(px + kb))[1];
            F[2] = ((const float4*)(px + kb))[2]; F[3] = ((const float4*)(px + kb))[3];
        }
        cvt8(F[4], F[5], h2, q2);
        cvt8(F[6], F[7], h3, q3);
        if (half == 0) ysum0 += s4(F[4]) + s4(F[5]) + s4(F[6]) + s4(F[7]);
        if (more) {
            F[4] = ((const float4*)(py0 + kb))[0]; F[5] = ((const float4*)(py0 + kb))[1];
            F[6] = ((const float4*)(py0 + kb))[2]; F[7] = ((const float4*)(py0 + kb))[3];
        }
        cvt8(F[8], F[9], h4, q4);
        cvt8(F[10], F[11], h5, q5);
        if (half == 0) ysum1 += s4(F[8]) + s4(F[9]) + s4(F[10]) + s4(F[11]);
        if (more) {
            F[8] = ((const float4*)(py1 + kb))[0];  F[9] = ((const float4*)(py1 + kb))[1];
            F[10] = ((const float4*)(py1 + kb))[2]; F[11] = ((const float4*)(py1 + kb))[3];
        }
        __syncthreads();                 // previous compute finished reading LDS
        *(uint4*)&XH[xo0] = h0; *(uint4*)&XL[xo0] = q0;
        *(uint4*)&XH[xo1] = h1; *(uint4*)&XL[xo1] = q1;
        *(uint4*)&YH[yo00] = h2; *(uint4*)&YL[yo00] = q2;
        *(uint4*)&YH[yo01] = h3; *(uint4*)&YL[yo01] = q3;
        *(uint4*)&YH[yo10] = h4; *(uint4*)&YL[yo10] = q4;
        *(uint4*)&YH[yo11] = h5; *(uint4*)&YL[yo11] = q5;
        __syncthreads();
        {
            int sl = swz(lane);
            s16x8 ah[4], al[4];
            #pragma unroll
            for (int i = 0; i < 4; ++i) {
                int fr = (wr * 4 + i) * 64 + sl;
                ah[i] = *(const s16x8*)&XH[fr * 8];
                al[i] = *(const s16x8*)&XL[fr * 8];
            }
            #pragma unroll
            for (int j = 0; j < 8; ++j) {
                int fr = (wc * 8 + j) * 64 + sl;
                s16x8 bh = *(const s16x8*)&YH[fr * 8];
                s16x8 bl = *(const s16x8*)&YL[fr * 8];
                #pragma unroll
                for (int i = 0; i < 4; ++i) {
                    acc[i][j] = __builtin_amdgcn_mfma_f32_16x16x32_bf16(ah[i], bh, acc[i][j], 0, 0, 0);
                    acc[i][j] = __builtin_amdgcn_mfma_f32_16x16x32_bf16(ah[i], bl, acc[i][j], 0, 0, 0);
                    acc[i][j] = __builtin_amdgcn_mfma_f32_16x16x32_bf16(al[i], bh, acc[i][j], 0, 0, 0);
                }
            }
        }
    }

    // row-sum partials (deterministic): combine kh pair via shfl
    float xs  = xsum  + __shfl_down(xsum, 1);
    float y0s = ysum0 + __shfl_down(ysum0, 1);
    float y1s = ysum1 + __shfl_down(ysum1, 1);
    if (!(tid & 1)) {
        sxp[((size_t)b * nsplit + ks) * 256 + half * 128 + r] = xs;
        if (half == 0) {
            syp[((size_t)b * nsplit + ks) * 256 + r] = y0s;
            syp[((size_t)b * nsplit + ks) * 256 + 128 + r] = y1s;
        }
    }

    // write partials (C/D: col = lane&15, row = (lane>>4)*4 + reg)
    float* P = part + ((size_t)b * nsplit + ks) * Cc * Cc;
    #pragma unroll
    for (int i = 0; i < 4; ++i)
        #pragma unroll
        for (int j = 0; j < 8; ++j)
            #pragma unroll
            for (int reg = 0; reg < 4; ++reg) {
                int gi = half * 128 + wr * 64 + i * 16 + (lane >> 4) * 4 + reg;
                int gj = wc * 128 + j * 16 + (lane & 15);
                P[(size_t)gi * Cc + gj] = acc[i][j][reg];
            }
}

// reduce S partials; blocks >=1024 reduce row-sum partials into sx/sy
__global__ __launch_bounds__(256) void k_reduceS(const float* __restrict__ part,
                                                 const float* __restrict__ sxp,
                                                 const float* __restrict__ syp,
                                                 float* __restrict__ S,
                                                 float* __restrict__ sx,
                                                 float* __restrict__ sy, int split) {
    if (blockIdx.x < 1024) {
        int t = blockIdx.x * 256 + threadIdx.x;   // 0..262143
        int b = t >> 16;
        int rc = t & 65535;
        float s = 0.f;
        for (int ks = 0; ks < split; ++ks)
            s += part[(((size_t)b * split + ks) << 16) + rc];
        S[t] = s;
    } else {
        int flat = (blockIdx.x - 1024) * 256 + threadIdx.x;  // 0..2047
        int b = flat >> 9, rem = flat & 511, which = rem >> 8, c = rem & 255;
        const float* src = (which ? syp : sxp) + (size_t)b * split * 256 + c;
        float s = 0.f;
        for (int ks = 0; ks < split; ++ks) s += src[(size_t)ks * 256];
        (which ? sy : sx)[b * 256 + c] = s;
    }
}

// T1[b,c,j] = sum_d S[b,c,d] * Wk[j,d]; tail blocks compute qx/ky
__global__ __launch_bounds__(256) void k_T1(const float* __restrict__ S,
                                            const float* __restrict__ Wk,
                                            const float* __restrict__ Wq,
                                            const float* __restrict__ sx,
                                            const float* __restrict__ sy,
                                            float* __restrict__ T1,
                                            float* __restrict__ qx,
                                            float* __restrict__ ky) {
    if (blockIdx.x < 1024) {
        int b = blockIdx.x >> 8;
        int c = blockIdx.x & 255;
        int j = threadIdx.x;
        __shared__ float srow[256];
        srow[j] = S[((size_t)b * Cc + c) * Cc + j];
        __syncthreads();
        const float4* wk4 = (const float4*)(Wk + (size_t)j * Cc);
        const float4* sr4 = (const float4*)srow;
        float s = 0.f;
        #pragma unroll 4
        for (int d = 0; d < Cc / 4; ++d) {
            float4 a = sr4[d]; float4 w = wk4[d];
            s += a.x * w.x + a.y * w.y + a.z * w.z + a.w * w.w;
        }
        T1[((size_t)b * Cc + c) * Cc + j] = s;
    } else {
        int t = (blockIdx.x - 1024) * 256 + threadIdx.x;   // 0..2047
        int which = t >> 10;
        int b = (t >> 8) & 3;
        int r = t & 255;
        const float* W  = which ? Wk : Wq;
        const float* sv = which ? sy : sx;
        float* dst      = which ? ky : qx;
        float s = 0.f;
        #pragma unroll 4
        for (int c = 0; c < Cc; ++c) s += W[r * Cc + c] * sv[b * Cc + c];
        dst[b * Cc + r] = s;
    }
}

// scores + softmax + cbias + M (fused):  one block per (b,i) row
// M[b,i,c] = sum_j softmax(scores)[j] * Wv[j,c]  -> bf16
__global__ __launch_bounds__(256) void k_softmaxM(const float* __restrict__ T1,
                                                  const float* __restrict__ Wq,
                                                  const float* __restrict__ bq,
                                                  const float* __restrict__ bk,
                                                  const float* __restrict__ qx,
                                                  const float* __restrict__ ky,
                                                  const float* __restrict__ bv,
                                                  const float* __restrict__ Wv,
                                                  short* __restrict__ Mbf,
                                                  float* __restrict__ cbias) {
    int b = blockIdx.x >> 8;
    int i = blockIdx.x & 255;
    int j = threadIdx.x;
    __shared__ float wq[256];
    __shared__ float wsh[256];
    __shared__ float red[256];
    wq[j] = Wq[i * Cc + j];
    __syncthreads();
    const float* t1 = T1 + (size_t)b * Cc * Cc + j;
    float s = 0.f;
    #pragma unroll 4
    for (int c = 0; c < Cc; ++c) s += wq[c] * t1[(size_t)c * Cc];
    s += qx[b * Cc + i] * bk[j] + bq[i] * (ky[b * Cc + j] + 32768.0f * bk[j]);

    red[j] = s; __syncthreads();
    for (int st = 128; st > 0; st >>= 1) {
        if (j < st) red[j] = fmaxf(red[j], red[j + st]);
        __syncthreads();
    }
    float mx = red[0];
    __syncthreads();
    float e = expf(s - mx);
    red[j] = e; __syncthreads();
    for (int st = 128; st > 0; st >>= 1) {
        if (j < st) red[j] += red[j + st];
        __syncthreads();
    }
    float w = e / red[0];
    __syncthreads();
    wsh[j] = w;
    red[j] = w * bv[j]; __syncthreads();
    for (int st = 128; st > 0; st >>= 1) {
        if (j < st) red[j] += red[j + st];
        __syncthreads();
    }
    if (j == 0) cbias[b * Cc + i] = red[0];

    // M row: thread j plays role of output channel c = j
    float m = 0.f;
    #pragma unroll 4
    for (int jj = 0; jj < Cc; ++jj) m += wsh[jj] * Wv[(size_t)jj * Cc + j];
    Mbf[((size_t)b * Cc + i) * Cc + j] = (short)bfh(m);
}

// out[b,i,n] = sum_c M[b,i,c]*y[b,c,n] + cb[b,i]   (bf16 MFMA, Y prefetched)
__global__ __launch_bounds__(256, 2) void k_out_mfma(const short* __restrict__ Mbf,
                                                     const float* __restrict__ y,
                                                     const float* __restrict__ cb,
                                                     float* __restrict__ out) {
    int tid = threadIdx.x;
    int lane = tid & 63;
    int wave = tid >> 6;
    int bid = blockIdx.x;           // 0..1023
    int b = bid >> 8, grp = bid & 255;
    int nbase = grp * 128 + wave * 32;
    const float* Y = y + (size_t)b * Cc * Nn;
    const short* M = Mbf + (size_t)b * Cc * Cc;

    f32x4 acc[16][2];
    #pragma unroll
    for (int ti = 0; ti < 16; ++ti)
        #pragma unroll
        for (int nb = 0; nb < 2; ++nb)
            #pragma unroll
            for (int z = 0; z < 4; ++z) acc[ti][nb][z] = 0.f;

    float yv0[8], yv1[8];
    {
        int c0 = 8 * (lane >> 4);
        #pragma unroll
        for (int j = 0; j < 8; ++j) {
            yv0[j] = Y[(size_t)(c0 + j) * Nn + nbase + (lane & 15)];
            yv1[j] = Y[(size_t)(c0 + j) * Nn + nbase + 16 + (lane & 15)];
        }
    }
    for (int s = 0; s < 8; ++s) {
        int c0 = 32 * s + 8 * (lane >> 4);
        s16x8 bf0, bf1;
        #pragma unroll
        for (int j = 0; j < 8; ++j) {
            bf0[j] = (short)bfh(yv0[j]);
            bf1[j] = (short)bfh(yv1[j]);
        }
        if (s + 1 < 8) {                       // issue next-step loads early
            int c0n = 32 * (s + 1) + 8 * (lane >> 4);
            #pragma unroll
            for (int j = 0; j < 8; ++j) {
                yv0[j] = Y[(size_t)(c0n + j) * Nn + nbase + (lane & 15)];
                yv1[j] = Y[(size_t)(c0n + j) * Nn + nbase + 16 + (lane & 15)];
            }
        }
        #pragma unroll
        for (int ti = 0; ti < 16; ++ti) {
            s16x8 af = *(const s16x8*)&M[(size_t)(ti * 16 + (lane & 15)) * Cc + c0];
            acc[ti][0] = __builtin_amdgcn_mfma_f32_16x16x32_bf16(af, bf0, acc[ti][0], 0, 0, 0);
            acc[ti][1] = __builtin_amdgcn_mfma_f32_16x16x32_bf16(af, bf1, acc[ti][1], 0, 0, 0);
        }
    }
    #pragma unroll
    for (int ti = 0; ti < 16; ++ti)
        #pragma unroll
        for (int nb = 0; nb < 2; ++nb)
            #pragma unroll
            for (int reg = 0; reg < 4; ++reg) {
                int i = ti * 16 + (lane >> 4) * 4 + reg;
                out[((size_t)b * Cc + i) * Nn + nbase + nb * 16 + (lane & 15)] =
                    acc[ti][nb][reg] + cb[b * Cc + i];
            }
}

extern "C" void kernel_launch(void* const* d_in, const int* in_sizes, int n_in,
                              void* d_out, int out_size, void* d_ws, size_t ws_size,
                              hipStream_t stream) {
    const float* x  = (const float*)d_in[0];
    const float* y  = (const float*)d_in[1];
    const float* Wq = (const float*)d_in[2];
    const float* bq = (const float*)d_in[3];
    const float* Wk = (const float*)d_in[4];
    const float* bk = (const float*)d_in[5];
    const float* Wv = (const float*)d_in[6];
    const float* bv = (const float*)d_in[7];
    float* out = (float*)d_out;

    float* ws = (float*)d_ws;
    size_t off = 0;
    float* S  = ws + off; off += (size_t)Bb * Cc * Cc;
    float* sx = ws + off; off += Bb * Cc;
    float* sy = ws + off; off += Bb * Cc;
    float* qx = ws + off; off += Bb * Cc;
    float* ky = ws + off; off += Bb * Cc;
    float* T1 = ws + off; off += (size_t)Bb * Cc * Cc;
    short* Mbf = (short*)(ws + off); off += (size_t)Bb * Cc * Cc / 2;
    float* cb = ws + off; off += Bb * Cc;
    float* sxp = ws + off; off += (size_t)Bb * 64 * 256;
    float* syp = ws + off; off += (size_t)Bb * 64 * 256;
    float* part = ws + off;

    size_t avail = ws_size / 4 - off;
    int split = 64;
    while (split > 16 && (size_t)split * Bb * Cc * Cc > avail) split >>= 1;

    k_gram<<<Bb * split * 2, 256, 0, stream>>>(x, y, part, sxp, syp, split);
    k_reduceS<<<1032, 256, 0, stream>>>(part, sxp, syp, S, sx, sy, split);
    k_T1<<<1032, 256, 0, stream>>>(S, Wk, Wq, sx, sy, T1, qx, ky);
    k_softmaxM<<<1024, 256, 0, stream>>>(T1, Wq, bq, bk, qx, ky, bv, Wv, Mbf, cb);
    k_out_mfma<<<1024, 256, 0, stream>>>(Mbf, y, cb, out);
}

// Round 6
// 256.296 us; speedup vs baseline: 1.3948x; 1.2039x over previous
//
#include <hip/hip_runtime.h>

#define Bb 4
#define Cc 256
#define Nn 32768

typedef short s16x8 __attribute__((ext_vector_type(8)));
typedef float f32x4 __attribute__((ext_vector_type(4)));

__device__ __forceinline__ unsigned short bfh(float f) {
    union { float f; unsigned u; } c; c.f = f;
    unsigned u = c.u + 0x7fffu + ((c.u >> 16) & 1u);
    return (unsigned short)(u >> 16);
}
__device__ __forceinline__ unsigned fbits(float f) {
    union { float f; unsigned u; } c; c.f = f; return c.u;
}
__device__ __forceinline__ float fof(unsigned u) {
    union { unsigned u; float f; } c; c.u = u; return c.f;
}
__device__ __forceinline__ int swz(int l) { return l ^ ((l >> 3) & 6); }

// hi = trunc-bf16 (top 16 bits), lo = rtn-bf16 of residual. 8 floats -> 2x uint4.
__device__ __forceinline__ void cvt8(float4 A, float4 B, uint4& h, uint4& l) {
    unsigned a0 = fbits(A.x), a1 = fbits(A.y), a2 = fbits(A.z), a3 = fbits(A.w);
    unsigned b0 = fbits(B.x), b1 = fbits(B.y), b2 = fbits(B.z), b3 = fbits(B.w);
    h.x = __builtin_amdgcn_perm(a1, a0, 0x07060302u);
    h.y = __builtin_amdgcn_perm(a3, a2, 0x07060302u);
    h.z = __builtin_amdgcn_perm(b1, b0, 0x07060302u);
    h.w = __builtin_amdgcn_perm(b3, b2, 0x07060302u);
    unsigned l0 = fbits(A.x - fof(a0 & 0xffff0000u)) + 0x8000u;
    unsigned l1 = fbits(A.y - fof(a1 & 0xffff0000u)) + 0x8000u;
    unsigned l2 = fbits(A.z - fof(a2 & 0xffff0000u)) + 0x8000u;
    unsigned l3 = fbits(A.w - fof(a3 & 0xffff0000u)) + 0x8000u;
    unsigned m0 = fbits(B.x - fof(b0 & 0xffff0000u)) + 0x8000u;
    unsigned m1 = fbits(B.y - fof(b1 & 0xffff0000u)) + 0x8000u;
    unsigned m2 = fbits(B.z - fof(b2 & 0xffff0000u)) + 0x8000u;
    unsigned m3 = fbits(B.w - fof(b3 & 0xffff0000u)) + 0x8000u;
    l.x = __builtin_amdgcn_perm(l1, l0, 0x07060302u);
    l.y = __builtin_amdgcn_perm(l3, l2, 0x07060302u);
    l.z = __builtin_amdgcn_perm(m1, m0, 0x07060302u);
    l.w = __builtin_amdgcn_perm(m3, m2, 0x07060302u);
}
__device__ __forceinline__ float s4(float4 v) { return (v.x + v.y) + (v.z + v.w); }

// ---------------- Gram partials via bf16x3 MFMA, 512 threads / 8 waves -------
// tile 128x256 per (b,ks,half); grid 512 = 2 blocks/CU; TLP hides load latency
__global__ __launch_bounds__(512, 4) void k_gram(const float* __restrict__ x,
                                                 const float* __restrict__ y,
                                                 float* __restrict__ part,
                                                 float* __restrict__ sxp,
                                                 float* __restrict__ syp,
                                                 int nsplit) {
    int G = Bb * nsplit * 2;                    // 512 when split=64
    int chunk = G >> 3;
    int lid = blockIdx.x;
    int bid = (lid & 7) * chunk + (lid >> 3);   // bijective: sibling halves same XCD

    int half = bid & 1;
    int ks = (bid >> 1) % nsplit;
    int b = bid / (2 * nsplit);
    int Kblk = Nn / nsplit;
    int nstep = Kblk >> 5;

    const float* X = x + (size_t)b * Cc * Nn + (size_t)(half * 128) * Nn + (size_t)ks * Kblk;
    const float* Y = y + (size_t)b * Cc * Nn + (size_t)ks * Kblk;

    __shared__ __align__(16) short XH[4096], XL[4096];
    __shared__ __align__(16) short YH[8192], YL[8192];

    int tid = threadIdx.x;
    int lane = tid & 63;
    int wave = tid >> 6;
    int wr = wave >> 2, wc = wave & 3;          // 2x4 wave grid, 64x64 each

    // X staging: thread t -> row xr (0..127), 8-col chunk xq (0..3)
    int xr = tid >> 2, xq = tid & 3;
    const float* px = X + (size_t)xr * Nn + xq * 8;
    int xl = (xr & 15) + 16 * xq;
    int xo = ((xr >> 4) * 64 + swz(xl)) * 8;
    // Y staging: thread t -> row yr (0..255), 16-col half yh2 (0..1)
    int yr = tid >> 1, yh2 = tid & 1;
    const float* py = Y + (size_t)yr * Nn + yh2 * 16;
    int yl0 = (yr & 15) + 32 * yh2, yl1 = yl0 + 16;
    int yo0 = ((yr >> 4) * 64 + swz(yl0)) * 8;
    int yo1 = ((yr >> 4) * 64 + swz(yl1)) * 8;

    f32x4 acc[4][4];
    #pragma unroll
    for (int i = 0; i < 4; ++i)
        #pragma unroll
        for (int j = 0; j < 4; ++j)
            #pragma unroll
            for (int z = 0; z < 4; ++z) acc[i][j][z] = 0.f;

    float xsum = 0.f, ysum = 0.f;

    for (int t = 0; t < nstep; ++t) {
        int kb = t * 32;
        float4 fx0 = ((const float4*)(px + kb))[0];
        float4 fx1 = ((const float4*)(px + kb))[1];
        float4 fy0 = ((const float4*)(py + kb))[0];
        float4 fy1 = ((const float4*)(py + kb))[1];
        float4 fy2 = ((const float4*)(py + kb))[2];
        float4 fy3 = ((const float4*)(py + kb))[3];
        uint4 hx, qx_, hy0, qy0, hy1, qy1;
        cvt8(fx0, fx1, hx, qx_);
        cvt8(fy0, fy1, hy0, qy0);
        cvt8(fy2, fy3, hy1, qy1);
        xsum += s4(fx0) + s4(fx1);
        if (half == 0) ysum += s4(fy0) + s4(fy1) + s4(fy2) + s4(fy3);
        __syncthreads();                 // previous compute finished reading LDS
        *(uint4*)&XH[xo] = hx;  *(uint4*)&XL[xo] = qx_;
        *(uint4*)&YH[yo0] = hy0; *(uint4*)&YL[yo0] = qy0;
        *(uint4*)&YH[yo1] = hy1; *(uint4*)&YL[yo1] = qy1;
        __syncthreads();
        {
            int sl = swz(lane);
            s16x8 ah[4], al[4];
            #pragma unroll
            for (int i = 0; i < 4; ++i) {
                int fr = (wr * 4 + i) * 64 + sl;
                ah[i] = *(const s16x8*)&XH[fr * 8];
                al[i] = *(const s16x8*)&XL[fr * 8];
            }
            #pragma unroll
            for (int j = 0; j < 4; ++j) {
                int fr = (wc * 4 + j) * 64 + sl;
                s16x8 bh = *(const s16x8*)&YH[fr * 8];
                s16x8 bl = *(const s16x8*)&YL[fr * 8];
                #pragma unroll
                for (int i = 0; i < 4; ++i) {
                    acc[i][j] = __builtin_amdgcn_mfma_f32_16x16x32_bf16(ah[i], bh, acc[i][j], 0, 0, 0);
                    acc[i][j] = __builtin_amdgcn_mfma_f32_16x16x32_bf16(ah[i], bl, acc[i][j], 0, 0, 0);
                    acc[i][j] = __builtin_amdgcn_mfma_f32_16x16x32_bf16(al[i], bh, acc[i][j], 0, 0, 0);
                }
            }
        }
    }

    // row-sum partials: X shared by 4 threads (xq), Y by 2 (yh2)
    xsum += __shfl_xor(xsum, 1);
    xsum += __shfl_xor(xsum, 2);
    ysum += __shfl_xor(ysum, 1);
    if (xq == 0) sxp[((size_t)b * nsplit + ks) * 256 + half * 128 + xr] = xsum;
    if (half == 0 && yh2 == 0) syp[((size_t)b * nsplit + ks) * 256 + yr] = ysum;

    // write partials (C/D: col = lane&15, row = (lane>>4)*4 + reg)
    float* P = part + ((size_t)b * nsplit + ks) * Cc * Cc;
    #pragma unroll
    for (int i = 0; i < 4; ++i)
        #pragma unroll
        for (int j = 0; j < 4; ++j)
            #pragma unroll
            for (int reg = 0; reg < 4; ++reg) {
                int gi = half * 128 + wr * 64 + i * 16 + (lane >> 4) * 4 + reg;
                int gj = wc * 64 + j * 16 + (lane & 15);
                P[(size_t)gi * Cc + gj] = acc[i][j][reg];
            }
}

// reduce S partials; blocks >=1024 reduce row-sum partials into sx/sy
__global__ __launch_bounds__(256) void k_reduceS(const float* __restrict__ part,
                                                 const float* __restrict__ sxp,
                                                 const float* __restrict__ syp,
                                                 float* __restrict__ S,
                                                 float* __restrict__ sx,
                                                 float* __restrict__ sy, int split) {
    if (blockIdx.x < 1024) {
        int t = blockIdx.x * 256 + threadIdx.x;   // 0..262143
        int b = t >> 16;
        int rc = t & 65535;
        float s = 0.f;
        for (int ks = 0; ks < split; ++ks)
            s += part[(((size_t)b * split + ks) << 16) + rc];
        S[t] = s;
    } else {
        int flat = (blockIdx.x - 1024) * 256 + threadIdx.x;  // 0..2047
        int b = flat >> 9, rem = flat & 511, which = rem >> 8, c = rem & 255;
        const float* src = (which ? syp : sxp) + (size_t)b * split * 256 + c;
        float s = 0.f;
        for (int ks = 0; ks < split; ++ks) s += src[(size_t)ks * 256];
        (which ? sy : sx)[b * 256 + c] = s;
    }
}

// ---------------- fused scores+softmax+M: 8 rows per block -------------------
// scores[ii][j] = sum_d u'[ii][d]*Wk[j,d] + (qx[ii]+N*bq[ii])*bk[j]
// u'[ii][d] = sum_c Wq[i,c]*S[b,c,d] + bq[ii]*sy[d];  qx[ii] = Wq[i,:]·sx
// M[ii][c] = sum_j softmax(scores)[ii][j] * Wv[j,c];  cb = sum_j w*bv[j]
__global__ __launch_bounds__(256) void k_attn(const float* __restrict__ S,
                                              const float* __restrict__ sx,
                                              const float* __restrict__ sy,
                                              const float* __restrict__ Wq,
                                              const float* __restrict__ Wk,
                                              const float* __restrict__ Wv,
                                              const float* __restrict__ bq,
                                              const float* __restrict__ bk,
                                              const float* __restrict__ bv,
                                              short* __restrict__ Mbf,
                                              float* __restrict__ cb) {
    __shared__ float wq_lds[8][256];
    __shared__ float u_lds[8][256];
    __shared__ float p_lds[8][256];
    __shared__ float wv_lds[32][256];
    __shared__ float sx_lds[256], sy_lds[256];
    __shared__ float qx_lds[8];

    int b = blockIdx.x >> 5;
    int i0 = (blockIdx.x & 31) << 3;
    int tid = threadIdx.x;
    int lane = tid & 63, wv4 = tid >> 6;

    float bqv[8];
    #pragma unroll
    for (int ii = 0; ii < 8; ++ii) {
        wq_lds[ii][tid] = Wq[(size_t)(i0 + ii) * Cc + tid];
        bqv[ii] = bq[i0 + ii];
    }
    sx_lds[tid] = sx[b * Cc + tid];
    sy_lds[tid] = sy[b * Cc + tid];
    __syncthreads();

    // ---- u-pass: thread owns column d = tid ----
    float u[8] = {};
    const float* Sb = S + (size_t)b * Cc * Cc + tid;
    #pragma unroll 4
    for (int c = 0; c < Cc; ++c) {
        float s = Sb[(size_t)c * Cc];
        #pragma unroll
        for (int ii = 0; ii < 8; ++ii) u[ii] += wq_lds[ii][c] * s;
    }
    #pragma unroll
    for (int ii = 0; ii < 8; ++ii) u_lds[ii][tid] = u[ii] + bqv[ii] * sy_lds[tid];

    // qx: wave wv4 handles rows 2*wv4, 2*wv4+1
    #pragma unroll
    for (int rr = 0; rr < 2; ++rr) {
        int ii = wv4 * 2 + rr;
        float p = 0.f;
        #pragma unroll
        for (int k = 0; k < 4; ++k) { int c = lane + 64 * k; p += wq_lds[ii][c] * sx_lds[c]; }
        #pragma unroll
        for (int m = 1; m < 64; m <<= 1) p += __shfl_xor(p, m);
        if (lane == 0) qx_lds[ii] = p;
    }
    __syncthreads();

    // ---- scores-pass: thread owns j = tid; Wk row chunks in registers ----
    float sc[8] = {};
    const float* WkRow = Wk + (size_t)tid * Cc;
    for (int ch = 0; ch < 8; ++ch) {
        float wkr[32];
        #pragma unroll
        for (int k = 0; k < 8; ++k)
            *(float4*)&wkr[4 * k] = ((const float4*)(WkRow + ch * 32))[k];
        #pragma unroll
        for (int dd = 0; dd < 32; ++dd) {
            float w = wkr[dd];
            #pragma unroll
            for (int ii = 0; ii < 8; ++ii) sc[ii] += u_lds[ii][ch * 32 + dd] * w;
        }
    }
    float bkj = bk[tid];
    #pragma unroll
    for (int ii = 0; ii < 8; ++ii) {
        sc[ii] += (qx_lds[ii] + 32768.0f * bqv[ii]) * bkj;
        p_lds[ii][tid] = sc[ii];
    }
    __syncthreads();

    // ---- softmax: wave wv4 handles rows 2*wv4, 2*wv4+1 ----
    #pragma unroll
    for (int rr = 0; rr < 2; ++rr) {
        int ii = wv4 * 2 + rr;
        float v0 = p_lds[ii][lane], v1 = p_lds[ii][lane + 64];
        float v2 = p_lds[ii][lane + 128], v3 = p_lds[ii][lane + 192];
        float mx = fmaxf(fmaxf(v0, v1), fmaxf(v2, v3));
        #pragma unroll
        for (int m = 1; m < 64; m <<= 1) mx = fmaxf(mx, __shfl_xor(mx, m));
        float e0 = expf(v0 - mx), e1 = expf(v1 - mx), e2 = expf(v2 - mx), e3 = expf(v3 - mx);
        float ssum = (e0 + e1) + (e2 + e3);
        #pragma unroll
        for (int m = 1; m < 64; m <<= 1) ssum += __shfl_xor(ssum, m);
        float inv = 1.0f / ssum;
        float w0 = e0 * inv, w1 = e1 * inv, w2 = e2 * inv, w3 = e3 * inv;
        p_lds[ii][lane] = w0; p_lds[ii][lane + 64] = w1;
        p_lds[ii][lane + 128] = w2; p_lds[ii][lane + 192] = w3;
        float cbp = w0 * bv[lane] + w1 * bv[lane + 64] + w2 * bv[lane + 128] + w3 * bv[lane + 192];
        #pragma unroll
        for (int m = 1; m < 64; m <<= 1) cbp += __shfl_xor(cbp, m);
        if (lane == 0) cb[b * Cc + i0 + ii] = cbp;
    }
    __syncthreads();

    // ---- M-pass: thread owns c = tid; Wv staged in 32-row LDS chunks ----
    float m[8] = {};
    for (int jc = 0; jc < 8; ++jc) {
        #pragma unroll
        for (int k = 0; k < 8; ++k) {
            int fidx = k * 256 + tid;           // 0..2047 float4s
            int jj = fidx >> 6, f4 = fidx & 63;
            *(float4*)&wv_lds[jj][4 * f4] =
                *(const float4*)(Wv + (size_t)(jc * 32 + jj) * Cc + 4 * f4);
        }
        __syncthreads();
        #pragma unroll 4
        for (int jj = 0; jj < 32; ++jj) {
            float w = wv_lds[jj][tid];
            #pragma unroll
            for (int ii = 0; ii < 8; ++ii) m[ii] += p_lds[ii][jc * 32 + jj] * w;
        }
        __syncthreads();
    }
    #pragma unroll
    for (int ii = 0; ii < 8; ++ii)
        Mbf[((size_t)(b * Cc + i0 + ii)) * Cc + tid] = (short)bfh(m[ii]);
}

// out[b,i,n] = sum_c M[b,i,c]*y[b,c,n] + cb[b,i]   (bf16 MFMA, Y prefetched)
__global__ __launch_bounds__(256, 2) void k_out_mfma(const short* __restrict__ Mbf,
                                                     const float* __restrict__ y,
                                                     const float* __restrict__ cb,
                                                     float* __restrict__ out) {
    int tid = threadIdx.x;
    int lane = tid & 63;
    int wave = tid >> 6;
    int bid = blockIdx.x;           // 0..1023
    int b = bid >> 8, grp = bid & 255;
    int nbase = grp * 128 + wave * 32;
    const float* Y = y + (size_t)b * Cc * Nn;
    const short* M = Mbf + (size_t)b * Cc * Cc;

    f32x4 acc[16][2];
    #pragma unroll
    for (int ti = 0; ti < 16; ++ti)
        #pragma unroll
        for (int nb = 0; nb < 2; ++nb)
            #pragma unroll
            for (int z = 0; z < 4; ++z) acc[ti][nb][z] = 0.f;

    float yv0[8], yv1[8];
    {
        int c0 = 8 * (lane >> 4);
        #pragma unroll
        for (int j = 0; j < 8; ++j) {
            yv0[j] = Y[(size_t)(c0 + j) * Nn + nbase + (lane & 15)];
            yv1[j] = Y[(size_t)(c0 + j) * Nn + nbase + 16 + (lane & 15)];
        }
    }
    for (int s = 0; s < 8; ++s) {
        int c0 = 32 * s + 8 * (lane >> 4);
        s16x8 bf0, bf1;
        #pragma unroll
        for (int j = 0; j < 8; ++j) {
            bf0[j] = (short)bfh(yv0[j]);
            bf1[j] = (short)bfh(yv1[j]);
        }
        if (s + 1 < 8) {                       // issue next-step loads early
            int c0n = 32 * (s + 1) + 8 * (lane >> 4);
            #pragma unroll
            for (int j = 0; j < 8; ++j) {
                yv0[j] = Y[(size_t)(c0n + j) * Nn + nbase + (lane & 15)];
                yv1[j] = Y[(size_t)(c0n + j) * Nn + nbase + 16 + (lane & 15)];
            }
        }
        #pragma unroll
        for (int ti = 0; ti < 16; ++ti) {
            s16x8 af = *(const s16x8*)&M[(size_t)(ti * 16 + (lane & 15)) * Cc + c0];
            acc[ti][0] = __builtin_amdgcn_mfma_f32_16x16x32_bf16(af, bf0, acc[ti][0], 0, 0, 0);
            acc[ti][1] = __builtin_amdgcn_mfma_f32_16x16x32_bf16(af, bf1, acc[ti][1], 0, 0, 0);
        }
    }
    #pragma unroll
    for (int ti = 0; ti < 16; ++ti)
        #pragma unroll
        for (int nb = 0; nb < 2; ++nb)
            #pragma unroll
            for (int reg = 0; reg < 4; ++reg) {
                int i = ti * 16 + (lane >> 4) * 4 + reg;
                out[((size_t)b * Cc + i) * Nn + nbase + nb * 16 + (lane & 15)] =
                    acc[ti][nb][reg] + cb[b * Cc + i];
            }
}

extern "C" void kernel_launch(void* const* d_in, const int* in_sizes, int n_in,
                              void* d_out, int out_size, void* d_ws, size_t ws_size,
                              hipStream_t stream) {
    const float* x  = (const float*)d_in[0];
    const float* y  = (const float*)d_in[1];
    const float* Wq = (const float*)d_in[2];
    const float* bq = (const float*)d_in[3];
    const float* Wk = (const float*)d_in[4];
    const float* bk = (const float*)d_in[5];
    const float* Wv = (const float*)d_in[6];
    const float* bv = (const float*)d_in[7];
    float* out = (float*)d_out;

    float* ws = (float*)d_ws;
    size_t off = 0;
    float* S  = ws + off; off += (size_t)Bb * Cc * Cc;
    float* sx = ws + off; off += Bb * Cc;
    float* sy = ws + off; off += Bb * Cc;
    short* Mbf = (short*)(ws + off); off += (size_t)Bb * Cc * Cc / 2;
    float* cb = ws + off; off += Bb * Cc;
    float* sxp = ws + off; off += (size_t)Bb * 64 * 256;
    float* syp = ws + off; off += (size_t)Bb * 64 * 256;
    float* part = ws + off;

    size_t avail = ws_size / 4 - off;
    int split = 64;
    while (split > 16 && (size_t)split * Bb * Cc * Cc > avail) split >>= 1;

    k_gram<<<Bb * split * 2, 512, 0, stream>>>(x, y, part, sxp, syp, split);
    k_reduceS<<<1032, 256, 0, stream>>>(part, sxp, syp, S, sx, sy, split);
    k_attn<<<Bb * 32, 256, 0, stream>>>(S, sx, sy, Wq, Wk, Wv, bq, bk, bv, Mbf, cb);
    k_out_mfma<<<1024, 256, 0, stream>>>(Mbf, y, cb, out);
}